// Round 1
// baseline (1063.347 us; speedup 1.0000x reference)
//
#include <hip/hip_runtime.h>
#include <hip/hip_bf16.h>

#define N_NODES 50000
#define D 128

// ---------------- init: zero deg, stats, pooled ----------------
__global__ void init_kernel(int* __restrict__ deg, float* __restrict__ stats,
                            float* __restrict__ pooled) {
    int i = blockIdx.x * blockDim.x + threadIdx.x;
    if (i < N_NODES) deg[i] = 0;
    if (i < 2048) stats[i] = 0.f;
    if (i < 640) pooled[i] = 0.f;
}

// ---------------- degree histogram ----------------
__global__ void hist_kernel(const int* __restrict__ dst, int* __restrict__ deg) {
    int e = blockIdx.x * 256 + threadIdx.x;
    atomicAdd(&deg[dst[e]], 1);
}

// ---------------- single-block exclusive scan (50000 elems) ----------------
__global__ __launch_bounds__(1024)
void scan_kernel(const int* __restrict__ deg, int* __restrict__ row_start,
                 int* __restrict__ cursor) {
    __shared__ int part[1024];
    int i = threadIdx.x;
    int base = i * 49;
    int end_ = min(base + 49, N_NODES);
    int s = 0;
    for (int j = base; j < end_; ++j) s += deg[j];
    part[i] = s;
    __syncthreads();
    for (int off = 1; off < 1024; off <<= 1) {
        int add = (i >= off) ? part[i - off] : 0;
        __syncthreads();
        part[i] += add;
        __syncthreads();
    }
    int run = (i == 0) ? 0 : part[i - 1];
    for (int j = base; j < end_; ++j) {
        row_start[j] = run;
        cursor[j] = run;
        run += deg[j];
    }
    if (i == 1023) row_start[N_NODES] = part[1023];
}

// ---------------- fill CSC edge list ----------------
__global__ void fill_kernel(const int* __restrict__ src, const int* __restrict__ dst,
                            int* __restrict__ cursor, int* __restrict__ esrc) {
    int e = blockIdx.x * 256 + threadIdx.x;
    int d = dst[e];
    int p = atomicAdd(&cursor[d], 1);
    esrc[p] = src[e];
}

// ---------------- aggregation: z[v] = h[v] + sum_{e->v} h[src] ----------------
// one wave (64 lanes) per node, float2 per lane = 512B coalesced row
__global__ __launch_bounds__(256)
void agg_kernel(const float* __restrict__ H, const int* __restrict__ esrc,
                const int* __restrict__ row_start, float* __restrict__ Z) {
    int v = blockIdx.x * 4 + (threadIdx.x >> 6);
    int lane = threadIdx.x & 63;
    int c2 = lane << 1;
    int beg = row_start[v], end_ = row_start[v + 1];
    float2 acc = *(const float2*)&H[v * D + c2];
    int e = beg;
    for (; e + 2 <= end_; e += 2) {
        int s0 = esrc[e], s1 = esrc[e + 1];
        float2 v0 = *(const float2*)&H[s0 * D + c2];
        float2 v1 = *(const float2*)&H[s1 * D + c2];
        acc.x += v0.x + v1.x;
        acc.y += v0.y + v1.y;
    }
    if (e < end_) {
        int s0 = esrc[e];
        float2 v0 = *(const float2*)&H[s0 * D + c2];
        acc.x += v0.x;
        acc.y += v0.y;
    }
    *(float2*)&Z[v * D + c2] = acc;
}

// ---------------- matmul: Y = f(X) @ W, f = identity or relu(bn) ----------------
// 128x128 row tile per block, 256 threads, 8x8 register blocking.
// Fused epilogue: per-column sum/sumsq of Y -> stats_out (for the next BN).
template <bool BN_IN>
__global__ __launch_bounds__(256)
void mm_kernel(const float* __restrict__ X, const float* __restrict__ W,
               const float* __restrict__ stats_in, const float* __restrict__ gam,
               const float* __restrict__ bet, float* __restrict__ Y,
               float* __restrict__ stats_out) {
    __shared__ float Wl[128][128];   // 64 KB
    __shared__ float As[8][128];     // 4 KB (reused as reduction buffer)
    __shared__ float ab[2][128];     // 1 KB

    int t = threadIdx.x;
    {
        const float4* W4 = (const float4*)W;
        float4* Wl4 = (float4*)Wl;
#pragma unroll
        for (int it = 0; it < 16; ++it) Wl4[it * 256 + t] = W4[it * 256 + t];
    }
    if (BN_IN && t < 128) {
        float s = stats_in[t] * (1.0f / N_NODES);
        float q = stats_in[128 + t] * (1.0f / N_NODES);
        float a = gam[t] * rsqrtf(q - s * s + 1e-5f);
        ab[0][t] = a;
        ab[1][t] = bet[t] - s * a;
    }
    __syncthreads();

    int rowbase = blockIdx.x * 128;
    int nrows = min(128, N_NODES - rowbase);
    int ty = t >> 4, tx = t & 15;

    float acc[8][8];
#pragma unroll
    for (int i = 0; i < 8; ++i)
#pragma unroll
        for (int j = 0; j < 8; ++j) acc[i][j] = 0.f;

    int lr = t >> 1;             // row this thread loads
    int kk0 = (t & 1) << 2;      // k sub-offset (0 or 4)

    for (int kb = 0; kb < 16; ++kb) {
        float4 v = make_float4(0.f, 0.f, 0.f, 0.f);
        if (lr < nrows) {
            v = *(const float4*)&X[(rowbase + lr) * D + (kb << 3) + kk0];
            if (BN_IN) {
                int cb = (kb << 3) + kk0;
                v.x = fmaxf(fmaf(ab[0][cb + 0], v.x, ab[1][cb + 0]), 0.f);
                v.y = fmaxf(fmaf(ab[0][cb + 1], v.y, ab[1][cb + 1]), 0.f);
                v.z = fmaxf(fmaf(ab[0][cb + 2], v.z, ab[1][cb + 2]), 0.f);
                v.w = fmaxf(fmaf(ab[0][cb + 3], v.w, ab[1][cb + 3]), 0.f);
            }
        }
        __syncthreads();
        As[kk0 + 0][lr] = v.x;
        As[kk0 + 1][lr] = v.y;
        As[kk0 + 2][lr] = v.z;
        As[kk0 + 3][lr] = v.w;
        __syncthreads();
#pragma unroll
        for (int kk = 0; kk < 8; ++kk) {
            float4 alo = *(const float4*)&As[kk][ty << 3];
            float4 ahi = *(const float4*)&As[kk][(ty << 3) + 4];
            float4 blo = *(const float4*)&Wl[(kb << 3) + kk][tx << 3];
            float4 bhi = *(const float4*)&Wl[(kb << 3) + kk][(tx << 3) + 4];
            float a8[8] = {alo.x, alo.y, alo.z, alo.w, ahi.x, ahi.y, ahi.z, ahi.w};
            float b8[8] = {blo.x, blo.y, blo.z, blo.w, bhi.x, bhi.y, bhi.z, bhi.w};
#pragma unroll
            for (int i = 0; i < 8; ++i)
#pragma unroll
                for (int j = 0; j < 8; ++j) acc[i][j] = fmaf(a8[i], b8[j], acc[i][j]);
        }
    }

    // store Y
#pragma unroll
    for (int i = 0; i < 8; ++i) {
        int r = (ty << 3) + i;
        if (r < nrows) {
            float4 o0 = make_float4(acc[i][0], acc[i][1], acc[i][2], acc[i][3]);
            float4 o1 = make_float4(acc[i][4], acc[i][5], acc[i][6], acc[i][7]);
            *(float4*)&Y[(rowbase + r) * D + (tx << 3)] = o0;
            *(float4*)&Y[(rowbase + r) * D + (tx << 3) + 4] = o1;
        }
    }

    // column sum / sumsq epilogue
    float psum[8], psq[8];
#pragma unroll
    for (int j = 0; j < 8; ++j) { psum[j] = 0.f; psq[j] = 0.f; }
#pragma unroll
    for (int i = 0; i < 8; ++i) {
        if ((ty << 3) + i < nrows) {
#pragma unroll
            for (int j = 0; j < 8; ++j) {
                float vv = acc[i][j];
                psum[j] += vv;
                psq[j] += vv * vv;
            }
        }
    }
#pragma unroll
    for (int j = 0; j < 8; ++j) {
        psum[j] += __shfl_xor(psum[j], 16);
        psum[j] += __shfl_xor(psum[j], 32);
        psq[j] += __shfl_xor(psq[j], 16);
        psq[j] += __shfl_xor(psq[j], 32);
    }
    __syncthreads();
    float* Red = &As[0][0];  // 1024 floats
    int wv = t >> 6, lane = t & 63;
    if (lane < 16) {
#pragma unroll
        for (int j = 0; j < 8; ++j) {
            Red[wv * 128 + (tx << 3) + j] = psum[j];
            Red[512 + wv * 128 + (tx << 3) + j] = psq[j];
        }
    }
    __syncthreads();
    if (t < 128) {
        float s = Red[t] + Red[128 + t] + Red[256 + t] + Red[384 + t];
        float q = Red[512 + t] + Red[640 + t] + Red[768 + t] + Red[896 + t];
        atomicAdd(&stats_out[t], s);
        atomicAdd(&stats_out[128 + t], q);
    }
}

// ---------------- apply relu(bn(Y)) -> Hout, and accumulate pooled ----------------
// TRANS=false: pure sum-pool of input (Hout unused).
template <bool TRANS>
__global__ __launch_bounds__(256)
void apply_pool_kernel(const float* __restrict__ Y, const float* __restrict__ stats,
                       const float* __restrict__ gam, const float* __restrict__ bet,
                       float* __restrict__ Hout, float* __restrict__ pooled) {
    __shared__ float abS[2][128];
    __shared__ float red[8][128];
    int t = threadIdx.x;
    if (TRANS && t < 128) {
        float s = stats[t] * (1.0f / N_NODES);
        float q = stats[128 + t] * (1.0f / N_NODES);
        float a = gam[t] * rsqrtf(q - s * s + 1e-5f);
        abS[0][t] = a;
        abS[1][t] = bet[t] - s * a;
    }
    __syncthreads();
    int c = (t & 31) << 2;
    int rrow = t >> 5;
    float4 A = make_float4(0.f, 0.f, 0.f, 0.f), B = A;
    if (TRANS) {
        A = *(const float4*)&abS[0][c];
        B = *(const float4*)&abS[1][c];
    }
    float4 p = make_float4(0.f, 0.f, 0.f, 0.f);
    for (int r = blockIdx.x * 8 + rrow; r < N_NODES; r += gridDim.x * 8) {
        float4 v = *(const float4*)&Y[r * D + c];
        if (TRANS) {
            v.x = fmaxf(fmaf(A.x, v.x, B.x), 0.f);
            v.y = fmaxf(fmaf(A.y, v.y, B.y), 0.f);
            v.z = fmaxf(fmaf(A.z, v.z, B.z), 0.f);
            v.w = fmaxf(fmaf(A.w, v.w, B.w), 0.f);
            *(float4*)&Hout[r * D + c] = v;
        }
        p.x += v.x; p.y += v.y; p.z += v.z; p.w += v.w;
    }
    *(float4*)&red[rrow][c] = p;
    __syncthreads();
    if (t < 128) {
        float s = 0.f;
#pragma unroll
        for (int i = 0; i < 8; ++i) s += red[i][t];
        atomicAdd(&pooled[t], s);
    }
}

// ---------------- prediction heads ----------------
__global__ void head_kernel(const float* __restrict__ pooled, const float* __restrict__ pW,
                            const float* __restrict__ pB, float* __restrict__ out) {
    int o = threadIdx.x;  // 64
    float acc = 0.f;
    for (int i = 0; i < 5; ++i) {
        acc += pB[i * 64 + o];
        const float* w = pW + i * 128 * 64;
        const float* p = pooled + i * 128;
        for (int cidx = 0; cidx < 128; ++cidx) acc += p[cidx] * w[cidx * 64 + o];
    }
    out[o] = acc;
}

extern "C" void kernel_launch(void* const* d_in, const int* in_sizes, int n_in,
                              void* d_out, int out_size, void* d_ws, size_t ws_size,
                              hipStream_t stream) {
    const float* h0 = (const float*)d_in[0];
    const int* src = (const int*)d_in[1];
    const int* dst = (const int*)d_in[2];
    const float* W1 = (const float*)d_in[3];
    const float* W2 = (const float*)d_in[4];
    const float* bn1_g = (const float*)d_in[5];
    const float* bn1_b = (const float*)d_in[6];
    const float* bn2_g = (const float*)d_in[7];
    const float* bn2_b = (const float*)d_in[8];
    const float* pW = (const float*)d_in[9];
    const float* pB = (const float*)d_in[10];
    float* out = (float*)d_out;

    char* ws = (char*)d_ws;
    float* h_cur = (float*)(ws + 0);            // 25.6 MB
    float* bufA = (float*)(ws + 25600000);      // z, then y2 (25.6 MB)
    float* bufB = (float*)(ws + 51200000);      // y1 (25.6 MB)
    int* esrc = (int*)(ws + 76800000);          // 3.2 MB
    int* deg = (int*)(ws + 80000000);           // 200 KB
    int* row_start = (int*)(ws + 80200000);     // 200.004 KB
    int* cursor = (int*)(ws + 80400016);        // 200 KB
    float* stats = (float*)(ws + 80600016);     // 8 KB: [bn1 x4][bn2 x4] each 256 f
    float* pooled = (float*)(ws + 80608208);    // 5*128 f

    init_kernel<<<196, 256, 0, stream>>>(deg, stats, pooled);
    hist_kernel<<<3125, 256, 0, stream>>>(dst, deg);
    scan_kernel<<<1, 1024, 0, stream>>>(deg, row_start, cursor);
    fill_kernel<<<3125, 256, 0, stream>>>(src, dst, cursor, esrc);
    apply_pool_kernel<false><<<1024, 256, 0, stream>>>(h0, nullptr, nullptr, nullptr,
                                                       nullptr, pooled);

    const float* hp = h0;
    for (int i = 0; i < 4; ++i) {
        agg_kernel<<<12500, 256, 0, stream>>>(hp, esrc, row_start, bufA);
        mm_kernel<false><<<391, 256, 0, stream>>>(bufA, W1 + i * 16384, nullptr, nullptr,
                                                  nullptr, bufB, stats + i * 256);
        mm_kernel<true><<<391, 256, 0, stream>>>(bufB, W2 + i * 16384, stats + i * 256,
                                                 bn1_g + i * 128, bn1_b + i * 128, bufA,
                                                 stats + (4 + i) * 256);
        apply_pool_kernel<true><<<1024, 256, 0, stream>>>(bufA, stats + (4 + i) * 256,
                                                          bn2_g + i * 128, bn2_b + i * 128,
                                                          h_cur, pooled + (i + 1) * 128);
        hp = h_cur;
    }
    head_kernel<<<1, 64, 0, stream>>>(pooled, pW, pB, out);
}

// Round 2
// 876.023 us; speedup vs baseline: 1.2138x; 1.2138x over previous
//
#include <hip/hip_runtime.h>
#include <hip/hip_bf16.h>

#define N_NODES 50000
#define N_EDGES 800000
#define D 128

// ---------------- init: zero deg, stats, pooled ----------------
__global__ void init_kernel(int* __restrict__ deg, float* __restrict__ stats,
                            float* __restrict__ pooled) {
    int i = blockIdx.x * blockDim.x + threadIdx.x;
    if (i < N_NODES) deg[i] = 0;
    if (i < 2048) stats[i] = 0.f;
    if (i < 640) pooled[i] = 0.f;
}

// ---------------- degree histogram ----------------
__global__ void hist_kernel(const int* __restrict__ dst, int* __restrict__ deg) {
    int e = blockIdx.x * 256 + threadIdx.x;
    atomicAdd(&deg[dst[e]], 1);
}

// ---------------- parallel scan, stage A: per-block sums (196 blocks) ----------------
__global__ __launch_bounds__(256)
void scanA_kernel(const int* __restrict__ deg, int* __restrict__ bsum) {
    __shared__ int red[256];
    int t = threadIdx.x;
    int g = blockIdx.x * 256 + t;
    red[t] = (g < N_NODES) ? deg[g] : 0;
    __syncthreads();
    for (int off = 128; off > 0; off >>= 1) {
        if (t < off) red[t] += red[t + off];
        __syncthreads();
    }
    if (t == 0) bsum[blockIdx.x] = red[0];
}

// ---------------- stage B: scan the 196 block sums (1 block) ----------------
__global__ __launch_bounds__(256)
void scanB_kernel(const int* __restrict__ bsum, int* __restrict__ boff) {
    __shared__ int s[256];
    int t = threadIdx.x;
    s[t] = (t < 196) ? bsum[t] : 0;
    __syncthreads();
    for (int off = 1; off < 256; off <<= 1) {
        int a = (t >= off) ? s[t - off] : 0;
        __syncthreads();
        s[t] += a;
        __syncthreads();
    }
    boff[t] = (t == 0) ? 0 : s[t - 1];
}

// ---------------- stage C: per-element exclusive offsets (196 blocks) ----------------
__global__ __launch_bounds__(256)
void scanC_kernel(const int* __restrict__ deg, const int* __restrict__ boff,
                  int* __restrict__ row_start, int* __restrict__ cursor) {
    __shared__ int s[256];
    int t = threadIdx.x;
    int g = blockIdx.x * 256 + t;
    int v = (g < N_NODES) ? deg[g] : 0;
    s[t] = v;
    __syncthreads();
    for (int off = 1; off < 256; off <<= 1) {
        int a = (t >= off) ? s[t - off] : 0;
        __syncthreads();
        s[t] += a;
        __syncthreads();
    }
    int excl = boff[blockIdx.x] + s[t] - v;
    if (g < N_NODES) {
        row_start[g] = excl;
        cursor[g] = excl;
    }
    if (blockIdx.x == 0 && t == 0) row_start[N_NODES] = N_EDGES;
}

// ---------------- fill CSC edge list ----------------
__global__ void fill_kernel(const int* __restrict__ src, const int* __restrict__ dst,
                            int* __restrict__ cursor, int* __restrict__ esrc) {
    int e = blockIdx.x * 256 + threadIdx.x;
    int d = dst[e];
    int p = atomicAdd(&cursor[d], 1);
    esrc[p] = src[e];
}

// ---------------- aggregation: z[v] = f(H[v]) + sum_{e->v} f(H[src]) ----------------
// APPLY: f = relu(bn(.)) using stats/gam/bet of the producing layer (fused, no
// materialized h). One wave per node, float2 per lane = 512B coalesced row.
template <bool APPLY>
__global__ __launch_bounds__(256)
void agg_kernel(const float* __restrict__ H, const int* __restrict__ esrc,
                const int* __restrict__ row_start, const float* __restrict__ stats,
                const float* __restrict__ gam, const float* __restrict__ bet,
                float* __restrict__ Z) {
    int v = blockIdx.x * 4 + (threadIdx.x >> 6);
    int lane = threadIdx.x & 63;
    int c2 = lane << 1;
    float a0 = 1.f, b0 = 0.f, a1 = 1.f, b1 = 0.f;
    if (APPLY) {
        float m0 = stats[c2] * (1.0f / N_NODES);
        float q0 = stats[128 + c2] * (1.0f / N_NODES);
        float g0 = gam[c2] * rsqrtf(q0 - m0 * m0 + 1e-5f);
        a0 = g0; b0 = bet[c2] - m0 * g0;
        float m1 = stats[c2 + 1] * (1.0f / N_NODES);
        float q1 = stats[128 + c2 + 1] * (1.0f / N_NODES);
        float g1 = gam[c2 + 1] * rsqrtf(q1 - m1 * m1 + 1e-5f);
        a1 = g1; b1 = bet[c2 + 1] - m1 * g1;
    }
    int beg = row_start[v], end_ = row_start[v + 1];
    float2 acc = *(const float2*)&H[v * D + c2];
    if (APPLY) {
        acc.x = fmaxf(fmaf(a0, acc.x, b0), 0.f);
        acc.y = fmaxf(fmaf(a1, acc.y, b1), 0.f);
    }
    int e = beg;
    for (; e + 2 <= end_; e += 2) {
        int s0 = esrc[e], s1 = esrc[e + 1];
        float2 v0 = *(const float2*)&H[s0 * D + c2];
        float2 v1 = *(const float2*)&H[s1 * D + c2];
        if (APPLY) {
            v0.x = fmaxf(fmaf(a0, v0.x, b0), 0.f);
            v0.y = fmaxf(fmaf(a1, v0.y, b1), 0.f);
            v1.x = fmaxf(fmaf(a0, v1.x, b0), 0.f);
            v1.y = fmaxf(fmaf(a1, v1.y, b1), 0.f);
        }
        acc.x += v0.x + v1.x;
        acc.y += v0.y + v1.y;
    }
    if (e < end_) {
        int s0 = esrc[e];
        float2 v0 = *(const float2*)&H[s0 * D + c2];
        if (APPLY) {
            v0.x = fmaxf(fmaf(a0, v0.x, b0), 0.f);
            v0.y = fmaxf(fmaf(a1, v0.y, b1), 0.f);
        }
        acc.x += v0.x;
        acc.y += v0.y;
    }
    *(float2*)&Z[v * D + c2] = acc;
}

// ---------------- matmul: Y = f(X) @ W, f = identity or relu(bn) ----------------
// 128x128 row tile per block, 256 threads, 8x8 register blocking, double-buffered As.
// Fused epilogue: per-column sum/sumsq of Y -> stats_out (for the next BN).
template <bool BN_IN>
__global__ __launch_bounds__(256)
void mm_kernel(const float* __restrict__ X, const float* __restrict__ W,
               const float* __restrict__ stats_in, const float* __restrict__ gam,
               const float* __restrict__ bet, float* __restrict__ Y,
               float* __restrict__ stats_out) {
    __shared__ float Wl[128][128];   // 64 KB
    __shared__ float As[2][8][128];  // 8 KB double-buffered
    __shared__ float ab[2][128];     // 1 KB

    int t = threadIdx.x;
    {
        const float4* W4 = (const float4*)W;
        float4* Wl4 = (float4*)Wl;
#pragma unroll
        for (int it = 0; it < 16; ++it) Wl4[it * 256 + t] = W4[it * 256 + t];
    }
    if (BN_IN && t < 128) {
        float s = stats_in[t] * (1.0f / N_NODES);
        float q = stats_in[128 + t] * (1.0f / N_NODES);
        float a = gam[t] * rsqrtf(q - s * s + 1e-5f);
        ab[0][t] = a;
        ab[1][t] = bet[t] - s * a;
    }

    int rowbase = blockIdx.x * 128;
    int nrows = min(128, N_NODES - rowbase);
    int ty = t >> 4, tx = t & 15;

    float acc[8][8];
#pragma unroll
    for (int i = 0; i < 8; ++i)
#pragma unroll
        for (int j = 0; j < 8; ++j) acc[i][j] = 0.f;

    int lr = t >> 1;             // row this thread loads
    int kk0 = (t & 1) << 2;      // k sub-offset (0 or 4)

    __syncthreads();  // ab ready (and Wl in flight; next sync covers it)

    // prologue: stage kb=0 into buffer 0
    {
        float4 v = make_float4(0.f, 0.f, 0.f, 0.f);
        if (lr < nrows) {
            v = *(const float4*)&X[(rowbase + lr) * D + kk0];
            if (BN_IN) {
                v.x = fmaxf(fmaf(ab[0][kk0 + 0], v.x, ab[1][kk0 + 0]), 0.f);
                v.y = fmaxf(fmaf(ab[0][kk0 + 1], v.y, ab[1][kk0 + 1]), 0.f);
                v.z = fmaxf(fmaf(ab[0][kk0 + 2], v.z, ab[1][kk0 + 2]), 0.f);
                v.w = fmaxf(fmaf(ab[0][kk0 + 3], v.w, ab[1][kk0 + 3]), 0.f);
            }
        }
        As[0][kk0 + 0][lr] = v.x;
        As[0][kk0 + 1][lr] = v.y;
        As[0][kk0 + 2][lr] = v.z;
        As[0][kk0 + 3][lr] = v.w;
    }

    for (int kb = 0; kb < 16; ++kb) {
        __syncthreads();  // As[kb&1] ready (and Wl on first pass)
        if (kb < 15) {
            float4 v = make_float4(0.f, 0.f, 0.f, 0.f);
            int cb = ((kb + 1) << 3) + kk0;
            if (lr < nrows) {
                v = *(const float4*)&X[(rowbase + lr) * D + cb];
                if (BN_IN) {
                    v.x = fmaxf(fmaf(ab[0][cb + 0], v.x, ab[1][cb + 0]), 0.f);
                    v.y = fmaxf(fmaf(ab[0][cb + 1], v.y, ab[1][cb + 1]), 0.f);
                    v.z = fmaxf(fmaf(ab[0][cb + 2], v.z, ab[1][cb + 2]), 0.f);
                    v.w = fmaxf(fmaf(ab[0][cb + 3], v.w, ab[1][cb + 3]), 0.f);
                }
            }
            int nb = (kb + 1) & 1;
            As[nb][kk0 + 0][lr] = v.x;
            As[nb][kk0 + 1][lr] = v.y;
            As[nb][kk0 + 2][lr] = v.z;
            As[nb][kk0 + 3][lr] = v.w;
        }
        int cu = kb & 1;
#pragma unroll
        for (int kk = 0; kk < 8; ++kk) {
            float4 alo = *(const float4*)&As[cu][kk][ty << 3];
            float4 ahi = *(const float4*)&As[cu][kk][(ty << 3) + 4];
            float4 blo = *(const float4*)&Wl[(kb << 3) + kk][tx << 3];
            float4 bhi = *(const float4*)&Wl[(kb << 3) + kk][(tx << 3) + 4];
            float a8[8] = {alo.x, alo.y, alo.z, alo.w, ahi.x, ahi.y, ahi.z, ahi.w};
            float b8[8] = {blo.x, blo.y, blo.z, blo.w, bhi.x, bhi.y, bhi.z, bhi.w};
#pragma unroll
            for (int i = 0; i < 8; ++i)
#pragma unroll
                for (int j = 0; j < 8; ++j) acc[i][j] = fmaf(a8[i], b8[j], acc[i][j]);
        }
    }

    // store Y
#pragma unroll
    for (int i = 0; i < 8; ++i) {
        int r = (ty << 3) + i;
        if (r < nrows) {
            float4 o0 = make_float4(acc[i][0], acc[i][1], acc[i][2], acc[i][3]);
            float4 o1 = make_float4(acc[i][4], acc[i][5], acc[i][6], acc[i][7]);
            *(float4*)&Y[(rowbase + r) * D + (tx << 3)] = o0;
            *(float4*)&Y[(rowbase + r) * D + (tx << 3) + 4] = o1;
        }
    }

    // column sum / sumsq epilogue
    float psum[8], psq[8];
#pragma unroll
    for (int j = 0; j < 8; ++j) { psum[j] = 0.f; psq[j] = 0.f; }
#pragma unroll
    for (int i = 0; i < 8; ++i) {
        if ((ty << 3) + i < nrows) {
#pragma unroll
            for (int j = 0; j < 8; ++j) {
                float vv = acc[i][j];
                psum[j] += vv;
                psq[j] += vv * vv;
            }
        }
    }
#pragma unroll
    for (int j = 0; j < 8; ++j) {
        psum[j] += __shfl_xor(psum[j], 16);
        psum[j] += __shfl_xor(psum[j], 32);
        psq[j] += __shfl_xor(psq[j], 16);
        psq[j] += __shfl_xor(psq[j], 32);
    }
    __syncthreads();
    float* Red = &As[0][0][0];  // 2048 floats available
    int wv = t >> 6, lane = t & 63;
    if (lane < 16) {
#pragma unroll
        for (int j = 0; j < 8; ++j) {
            Red[wv * 128 + (tx << 3) + j] = psum[j];
            Red[512 + wv * 128 + (tx << 3) + j] = psq[j];
        }
    }
    __syncthreads();
    if (t < 128) {
        float s = Red[t] + Red[128 + t] + Red[256 + t] + Red[384 + t];
        float q = Red[512 + t] + Red[640 + t] + Red[768 + t] + Red[896 + t];
        atomicAdd(&stats_out[t], s);
        atomicAdd(&stats_out[128 + t], q);
    }
}

// ---------------- pool: pooled += column-sum of f(Y); f = identity | relu(bn) ----------------
template <bool TRANS>
__global__ __launch_bounds__(256)
void pool_kernel(const float* __restrict__ Y, const float* __restrict__ stats,
                 const float* __restrict__ gam, const float* __restrict__ bet,
                 float* __restrict__ pooled) {
    __shared__ float abS[2][128];
    __shared__ float red[8][128];
    int t = threadIdx.x;
    if (TRANS && t < 128) {
        float s = stats[t] * (1.0f / N_NODES);
        float q = stats[128 + t] * (1.0f / N_NODES);
        float a = gam[t] * rsqrtf(q - s * s + 1e-5f);
        abS[0][t] = a;
        abS[1][t] = bet[t] - s * a;
    }
    __syncthreads();
    int c = (t & 31) << 2;
    int rrow = t >> 5;
    float4 A = make_float4(0.f, 0.f, 0.f, 0.f), B = A;
    if (TRANS) {
        A = *(const float4*)&abS[0][c];
        B = *(const float4*)&abS[1][c];
    }
    float4 p = make_float4(0.f, 0.f, 0.f, 0.f);
    for (int r = blockIdx.x * 8 + rrow; r < N_NODES; r += gridDim.x * 8) {
        float4 v = *(const float4*)&Y[r * D + c];
        if (TRANS) {
            v.x = fmaxf(fmaf(A.x, v.x, B.x), 0.f);
            v.y = fmaxf(fmaf(A.y, v.y, B.y), 0.f);
            v.z = fmaxf(fmaf(A.z, v.z, B.z), 0.f);
            v.w = fmaxf(fmaf(A.w, v.w, B.w), 0.f);
        }
        p.x += v.x; p.y += v.y; p.z += v.z; p.w += v.w;
    }
    *(float4*)&red[rrow][c] = p;
    __syncthreads();
    if (t < 128) {
        float s = 0.f;
#pragma unroll
        for (int i = 0; i < 8; ++i) s += red[i][t];
        atomicAdd(&pooled[t], s);
    }
}

// ---------------- prediction heads ----------------
__global__ void head_kernel(const float* __restrict__ pooled, const float* __restrict__ pW,
                            const float* __restrict__ pB, float* __restrict__ out) {
    int o = threadIdx.x;  // 64
    float acc = 0.f;
    for (int i = 0; i < 5; ++i) {
        acc += pB[i * 64 + o];
        const float* w = pW + i * 128 * 64;
        const float* p = pooled + i * 128;
        for (int cidx = 0; cidx < 128; ++cidx) acc += p[cidx] * w[cidx * 64 + o];
    }
    out[o] = acc;
}

extern "C" void kernel_launch(void* const* d_in, const int* in_sizes, int n_in,
                              void* d_out, int out_size, void* d_ws, size_t ws_size,
                              hipStream_t stream) {
    const float* h0 = (const float*)d_in[0];
    const int* src = (const int*)d_in[1];
    const int* dst = (const int*)d_in[2];
    const float* W1 = (const float*)d_in[3];
    const float* W2 = (const float*)d_in[4];
    const float* bn1_g = (const float*)d_in[5];
    const float* bn1_b = (const float*)d_in[6];
    const float* bn2_g = (const float*)d_in[7];
    const float* bn2_b = (const float*)d_in[8];
    const float* pW = (const float*)d_in[9];
    const float* pB = (const float*)d_in[10];
    float* out = (float*)d_out;

    char* ws = (char*)d_ws;
    float* bufX = (float*)(ws + 0);             // y2 ping (also z scratch) 25.6 MB
    float* bufY = (float*)(ws + 25600000);      // y2 pong (also z scratch) 25.6 MB
    float* bufZ = (float*)(ws + 51200000);      // y1 scratch 25.6 MB
    int* esrc = (int*)(ws + 76800000);          // 3.2 MB
    int* deg = (int*)(ws + 80000000);           // 200 KB
    int* row_start = (int*)(ws + 80200000);     // 200.004 KB
    int* cursor = (int*)(ws + 80400016);        // 200 KB
    int* bsum = (int*)(ws + 80600016);          // 196 ints
    int* boff = (int*)(ws + 80600800);          // 256 ints
    float* stats = (float*)(ws + 80601824);     // 8 KB: [bn1 x4][bn2 x4] each 256 f
    float* pooled = (float*)(ws + 80610016);    // 5*128 f

    init_kernel<<<196, 256, 0, stream>>>(deg, stats, pooled);
    hist_kernel<<<3125, 256, 0, stream>>>(dst, deg);
    scanA_kernel<<<196, 256, 0, stream>>>(deg, bsum);
    scanB_kernel<<<1, 256, 0, stream>>>(bsum, boff);
    scanC_kernel<<<196, 256, 0, stream>>>(deg, boff, row_start, cursor);
    fill_kernel<<<3125, 256, 0, stream>>>(src, dst, cursor, esrc);
    pool_kernel<false><<<512, 256, 0, stream>>>(h0, nullptr, nullptr, nullptr, pooled);

    // buffer rotation: z/y2 alternate bufX/bufY; y1 always bufZ
    for (int i = 0; i < 4; ++i) {
        const float* hprev = (i == 0) ? h0 : ((i & 1) ? bufX : bufY);
        float* zb = (i & 1) ? bufY : bufX;  // z and then y2 live here
        const float* pstats = stats + (4 + (i - 1)) * 256;
        if (i == 0) {
            agg_kernel<false><<<12500, 256, 0, stream>>>(hprev, esrc, row_start, nullptr,
                                                         nullptr, nullptr, zb);
        } else {
            agg_kernel<true><<<12500, 256, 0, stream>>>(hprev, esrc, row_start, pstats,
                                                        bn2_g + (i - 1) * 128,
                                                        bn2_b + (i - 1) * 128, zb);
        }
        mm_kernel<false><<<391, 256, 0, stream>>>(zb, W1 + i * 16384, nullptr, nullptr,
                                                  nullptr, bufZ, stats + i * 256);
        mm_kernel<true><<<391, 256, 0, stream>>>(bufZ, W2 + i * 16384, stats + i * 256,
                                                 bn1_g + i * 128, bn1_b + i * 128, zb,
                                                 stats + (4 + i) * 256);
        pool_kernel<true><<<512, 256, 0, stream>>>(zb, stats + (4 + i) * 256,
                                                   bn2_g + i * 128, bn2_b + i * 128,
                                                   pooled + (i + 1) * 128);
    }
    head_kernel<<<1, 64, 0, stream>>>(pooled, pW, pB, out);
}

// Round 3
// 692.378 us; speedup vs baseline: 1.5358x; 1.2652x over previous
//
#include <hip/hip_runtime.h>
#include <hip/hip_bf16.h>

#define N_NODES 50000
#define N_EDGES 800000
#define D 128

typedef __bf16 bf16;
typedef __attribute__((ext_vector_type(8))) __bf16 bf16x8;
typedef __attribute__((ext_vector_type(4))) __bf16 bf16x4;
typedef __attribute__((ext_vector_type(16))) float f32x16;

// ---------------- init: zero deg, stats, ppart, pooled4 ----------------
__global__ void init_kernel(int* __restrict__ deg, float* __restrict__ stats,
                            float* __restrict__ ppart, float* __restrict__ pooled4) {
    int i = blockIdx.x * blockDim.x + threadIdx.x;
    if (i < N_NODES) deg[i] = 0;
    if (i < 2048) stats[i] = 0.f;
    if (i < 32768) ppart[i] = 0.f;
    if (i < 128) pooled4[i] = 0.f;
}

// ---------------- W -> fragment-ordered bf16 hi/lo planes ----------------
// Frag layout (32x32x16 B-operand): col = lane&31, k = 8*(lane>>5)+j.
// Storage: Wf[m*16384 + ((cf*8+sub)*64 + lane)*8 + j], cf=col-frag, sub=K/16 chunk.
__global__ __launch_bounds__(256)
void prep_kernel(const float* __restrict__ W1, const float* __restrict__ W2,
                 bf16* __restrict__ WfH, bf16* __restrict__ WfL) {
    int gid = blockIdx.x * 256 + threadIdx.x;  // 0..16383
    int lane = gid & 63;
    int grp = gid >> 6;       // 0..255
    int sub = grp & 7;
    int cf = (grp >> 3) & 3;
    int m = grp >> 5;         // 0..7
    const float* Wsrc = (m < 4) ? (W1 + m * 16384) : (W2 + (m - 4) * 16384);
    int col = cf * 32 + (lane & 31);
    int kb = sub * 16 + 8 * (lane >> 5);
    bf16x8 h, l;
#pragma unroll
    for (int j = 0; j < 8; ++j) {
        float w = Wsrc[(kb + j) * 128 + col];
        bf16 hb = (bf16)w;
        bf16 lb = (bf16)(w - (float)hb);
        h[j] = hb;
        l[j] = lb;
    }
    int idx = m * 16384 + ((grp & 31) * 64 + lane) * 8;
    *(bf16x8*)&WfH[idx] = h;
    *(bf16x8*)&WfL[idx] = l;
}

// ---------------- degree histogram ----------------
__global__ void hist_kernel(const int* __restrict__ dst, int* __restrict__ deg) {
    int e = blockIdx.x * 256 + threadIdx.x;
    atomicAdd(&deg[dst[e]], 1);
}

// ---------------- parallel scan ----------------
__global__ __launch_bounds__(256)
void scanA_kernel(const int* __restrict__ deg, int* __restrict__ bsum) {
    __shared__ int red[256];
    int t = threadIdx.x;
    int g = blockIdx.x * 256 + t;
    red[t] = (g < N_NODES) ? deg[g] : 0;
    __syncthreads();
    for (int off = 128; off > 0; off >>= 1) {
        if (t < off) red[t] += red[t + off];
        __syncthreads();
    }
    if (t == 0) bsum[blockIdx.x] = red[0];
}

__global__ __launch_bounds__(256)
void scanB_kernel(const int* __restrict__ bsum, int* __restrict__ boff) {
    __shared__ int s[256];
    int t = threadIdx.x;
    s[t] = (t < 196) ? bsum[t] : 0;
    __syncthreads();
    for (int off = 1; off < 256; off <<= 1) {
        int a = (t >= off) ? s[t - off] : 0;
        __syncthreads();
        s[t] += a;
        __syncthreads();
    }
    boff[t] = (t == 0) ? 0 : s[t - 1];
}

__global__ __launch_bounds__(256)
void scanC_kernel(const int* __restrict__ deg, const int* __restrict__ boff,
                  int* __restrict__ row_start, int* __restrict__ cursor) {
    __shared__ int s[256];
    int t = threadIdx.x;
    int g = blockIdx.x * 256 + t;
    int v = (g < N_NODES) ? deg[g] : 0;
    s[t] = v;
    __syncthreads();
    for (int off = 1; off < 256; off <<= 1) {
        int a = (t >= off) ? s[t - off] : 0;
        __syncthreads();
        s[t] += a;
        __syncthreads();
    }
    int excl = boff[blockIdx.x] + s[t] - v;
    if (g < N_NODES) {
        row_start[g] = excl;
        cursor[g] = excl;
    }
    if (blockIdx.x == 0 && t == 0) row_start[N_NODES] = N_EDGES;
}

// ---------------- fill CSC edge list ----------------
__global__ void fill_kernel(const int* __restrict__ src, const int* __restrict__ dst,
                            int* __restrict__ cursor, int* __restrict__ esrc) {
    int e = blockIdx.x * 256 + threadIdx.x;
    int d = dst[e];
    int p = atomicAdd(&cursor[d], 1);
    esrc[p] = src[e];
}

// ---------------- aggregation + fused input-pool ----------------
// z[v] = f(H[v]) + sum_{e->v} f(H[src]); f = identity | relu(bn).
// The self-term f(H[v]) is also the pool contribution of node v -> ppart.
template <bool APPLY>
__global__ __launch_bounds__(256)
void agg_kernel(const float* __restrict__ H, const int* __restrict__ esrc,
                const int* __restrict__ row_start, const float* __restrict__ stats,
                const float* __restrict__ gam, const float* __restrict__ bet,
                float* __restrict__ Z, float* __restrict__ ppart) {
    __shared__ float sred[4][128];
    int wv = threadIdx.x >> 6;
    int v = blockIdx.x * 4 + wv;
    int lane = threadIdx.x & 63;
    int c2 = lane << 1;
    float a0 = 1.f, b0 = 0.f, a1 = 1.f, b1 = 0.f;
    if (APPLY) {
        float m0 = stats[c2] * (1.0f / N_NODES);
        float q0 = stats[128 + c2] * (1.0f / N_NODES);
        float g0 = gam[c2] * rsqrtf(q0 - m0 * m0 + 1e-5f);
        a0 = g0; b0 = bet[c2] - m0 * g0;
        float m1 = stats[c2 + 1] * (1.0f / N_NODES);
        float q1 = stats[128 + c2 + 1] * (1.0f / N_NODES);
        float g1 = gam[c2 + 1] * rsqrtf(q1 - m1 * m1 + 1e-5f);
        a1 = g1; b1 = bet[c2 + 1] - m1 * g1;
    }
    int beg = row_start[v], end_ = row_start[v + 1];
    float2 self = *(const float2*)&H[v * D + c2];
    if (APPLY) {
        self.x = fmaxf(fmaf(a0, self.x, b0), 0.f);
        self.y = fmaxf(fmaf(a1, self.y, b1), 0.f);
    }
    *(float2*)&sred[wv][c2] = self;
    float2 acc = self;
    int e = beg;
    for (; e + 2 <= end_; e += 2) {
        int s0 = esrc[e], s1 = esrc[e + 1];
        float2 v0 = *(const float2*)&H[s0 * D + c2];
        float2 v1 = *(const float2*)&H[s1 * D + c2];
        if (APPLY) {
            v0.x = fmaxf(fmaf(a0, v0.x, b0), 0.f);
            v0.y = fmaxf(fmaf(a1, v0.y, b1), 0.f);
            v1.x = fmaxf(fmaf(a0, v1.x, b0), 0.f);
            v1.y = fmaxf(fmaf(a1, v1.y, b1), 0.f);
        }
        acc.x += v0.x + v1.x;
        acc.y += v0.y + v1.y;
    }
    if (e < end_) {
        int s0 = esrc[e];
        float2 v0 = *(const float2*)&H[s0 * D + c2];
        if (APPLY) {
            v0.x = fmaxf(fmaf(a0, v0.x, b0), 0.f);
            v0.y = fmaxf(fmaf(a1, v0.y, b1), 0.f);
        }
        acc.x += v0.x;
        acc.y += v0.y;
    }
    *(float2*)&Z[v * D + c2] = acc;
    __syncthreads();
    int t = threadIdx.x;
    if (t < 128) {
        float s = sred[0][t] + sred[1][t] + sred[2][t] + sred[3][t];
        atomicAdd(&ppart[(blockIdx.x & 63) * 128 + t], s);
    }
}

// ---------------- matmul: Y = f(X) @ W via split-bf16 MFMA ----------------
// 128-row tile/block, 4 waves; wave w owns cols [32w,32w+32), all 128 rows.
// B (weights) hi/lo fragments in registers; A (X) staged per K=32 chunk in LDS.
// 4 MFMA passes (hh, hl, lh, ll) => ~fp32 accuracy. Epilogue: col sum/sumsq.
template <bool BN_IN>
__global__ __launch_bounds__(256, 2)
void mm_kernel(const float* __restrict__ X, const bf16* __restrict__ WfH,
               const bf16* __restrict__ WfL, const float* __restrict__ stats_in,
               const float* __restrict__ gam, const float* __restrict__ bet,
               float* __restrict__ Y, float* __restrict__ stats_out) {
    __shared__ bf16 Ah[4096];  // [128 rows][32 k], XOR-swizzled
    __shared__ bf16 Al[4096];
    __shared__ float ab[2][128];

    int t = threadIdx.x;
    int w = t >> 6, lane = t & 63;
    if (BN_IN && t < 128) {
        float s = stats_in[t] * (1.0f / N_NODES);
        float q = stats_in[128 + t] * (1.0f / N_NODES);
        float a = gam[t] * rsqrtf(q - s * s + 1e-5f);
        ab[0][t] = a;
        ab[1][t] = bet[t] - s * a;
    }

    // B fragments -> registers (same for every block; L2-hot)
    bf16x8 Bh[8], Bl[8];
#pragma unroll
    for (int c = 0; c < 8; ++c) {
        int idx = ((w * 8 + c) * 64 + lane) * 8;
        Bh[c] = *(const bf16x8*)&WfH[idx];
        Bl[c] = *(const bf16x8*)&WfL[idx];
    }

    f32x16 acc[4];
#pragma unroll
    for (int fr = 0; fr < 4; ++fr) acc[fr] = (f32x16)0.0f;

    int rowbase = blockIdx.x * 128;
    int nrows = min(128, N_NODES - rowbase);
    int srow = t >> 1;           // staging row
    int sk0 = (t & 1) * 16;      // staging k base (16 floats per thread)
    __syncthreads();             // ab ready

    for (int kb = 0; kb < 4; ++kb) {
        if (kb) __syncthreads();  // previous chunk's reads done
        // ---- stage chunk [128][32] as hi/lo bf16, XOR-swizzled ----
        {
            bool ok = srow < nrows;
            const float* xr = &X[(rowbase + srow) * 128 + kb * 32 + sk0];
#pragma unroll
            for (int i = 0; i < 4; ++i) {
                float4 v = make_float4(0.f, 0.f, 0.f, 0.f);
                if (ok) {
                    v = *(const float4*)&xr[i * 4];
                    if (BN_IN) {
                        int kg = kb * 32 + sk0 + i * 4;
                        v.x = fmaxf(fmaf(ab[0][kg + 0], v.x, ab[1][kg + 0]), 0.f);
                        v.y = fmaxf(fmaf(ab[0][kg + 1], v.y, ab[1][kg + 1]), 0.f);
                        v.z = fmaxf(fmaf(ab[0][kg + 2], v.z, ab[1][kg + 2]), 0.f);
                        v.w = fmaxf(fmaf(ab[0][kg + 3], v.w, ab[1][kg + 3]), 0.f);
                    }
                }
                bf16x4 h4, l4;
                h4[0] = (bf16)v.x; l4[0] = (bf16)(v.x - (float)h4[0]);
                h4[1] = (bf16)v.y; l4[1] = (bf16)(v.y - (float)h4[1]);
                h4[2] = (bf16)v.z; l4[2] = (bf16)(v.z - (float)h4[2]);
                h4[3] = (bf16)v.w; l4[3] = (bf16)(v.w - (float)h4[3]);
                int e = srow * 32 + sk0 + i * 4;
                int es = e ^ ((srow & 7) << 3);
                *(bf16x4*)&Ah[es] = h4;
                *(bf16x4*)&Al[es] = l4;
            }
        }
        __syncthreads();
        // ---- compute: 2 K16 sub-chunks x 4 row-frags x 4 passes ----
#pragma unroll
        for (int s2 = 0; s2 < 2; ++s2) {
            int sg = kb * 2 + s2;
#pragma unroll
            for (int fr = 0; fr < 4; ++fr) {
                int row = fr * 32 + (lane & 31);
                int e = row * 32 + s2 * 16 + 8 * (lane >> 5);
                int es = e ^ ((row & 7) << 3);
                bf16x8 ah = *(const bf16x8*)&Ah[es];
                bf16x8 al = *(const bf16x8*)&Al[es];
                acc[fr] = __builtin_amdgcn_mfma_f32_32x32x16_bf16(al, Bl[sg], acc[fr], 0, 0, 0);
                acc[fr] = __builtin_amdgcn_mfma_f32_32x32x16_bf16(al, Bh[sg], acc[fr], 0, 0, 0);
                acc[fr] = __builtin_amdgcn_mfma_f32_32x32x16_bf16(ah, Bl[sg], acc[fr], 0, 0, 0);
                acc[fr] = __builtin_amdgcn_mfma_f32_32x32x16_bf16(ah, Bh[sg], acc[fr], 0, 0, 0);
            }
        }
    }

    // ---- epilogue: store Y + per-column sum/sumsq ----
    // C/D frag: col = lane&31, row = (reg&3) + 8*(reg>>2) + 4*(lane>>5)
    int col = w * 32 + (lane & 31);
    float psum = 0.f, psq = 0.f;
#pragma unroll
    for (int fr = 0; fr < 4; ++fr) {
#pragma unroll
        for (int r = 0; r < 16; ++r) {
            float v = acc[fr][r];
            int row = fr * 32 + (r & 3) + 8 * (r >> 2) + 4 * (lane >> 5);
            if (row < nrows) Y[(rowbase + row) * 128 + col] = v;
            psum += v;
            psq += v * v;
        }
    }
    psum += __shfl_xor(psum, 32);
    psq += __shfl_xor(psq, 32);
    if (lane < 32) {
        atomicAdd(&stats_out[col], psum);
        atomicAdd(&stats_out[128 + col], psq);
    }
}

// ---------------- final pool: pooled4 += column-sum of relu(bn(Y)) ----------------
__global__ __launch_bounds__(256)
void pool_kernel(const float* __restrict__ Y, const float* __restrict__ stats,
                 const float* __restrict__ gam, const float* __restrict__ bet,
                 float* __restrict__ pooled4) {
    __shared__ float abS[2][128];
    __shared__ float red[8][128];
    int t = threadIdx.x;
    if (t < 128) {
        float s = stats[t] * (1.0f / N_NODES);
        float q = stats[128 + t] * (1.0f / N_NODES);
        float a = gam[t] * rsqrtf(q - s * s + 1e-5f);
        abS[0][t] = a;
        abS[1][t] = bet[t] - s * a;
    }
    __syncthreads();
    int c = (t & 31) << 2;
    int rrow = t >> 5;
    float4 A = *(const float4*)&abS[0][c];
    float4 B = *(const float4*)&abS[1][c];
    float4 p = make_float4(0.f, 0.f, 0.f, 0.f);
    for (int r = blockIdx.x * 8 + rrow; r < N_NODES; r += gridDim.x * 8) {
        float4 v = *(const float4*)&Y[r * D + c];
        p.x += fmaxf(fmaf(A.x, v.x, B.x), 0.f);
        p.y += fmaxf(fmaf(A.y, v.y, B.y), 0.f);
        p.z += fmaxf(fmaf(A.z, v.z, B.z), 0.f);
        p.w += fmaxf(fmaf(A.w, v.w, B.w), 0.f);
    }
    *(float4*)&red[rrow][c] = p;
    __syncthreads();
    if (t < 128) {
        float s = 0.f;
#pragma unroll
        for (int i = 0; i < 8; ++i) s += red[i][t];
        atomicAdd(&pooled4[t], s);
    }
}

// ---------------- heads: reduce ppart, apply prediction layers ----------------
__global__ void head_kernel(const float* __restrict__ ppart, const float* __restrict__ pooled4,
                            const float* __restrict__ pW, const float* __restrict__ pB,
                            float* __restrict__ out) {
    __shared__ float pl[5][128];
    int t = threadIdx.x;  // 128
    if (t < 128) {
        for (int l = 0; l < 4; ++l) {
            float s = 0.f;
            for (int sl = 0; sl < 64; ++sl) s += ppart[(l * 64 + sl) * 128 + t];
            pl[l][t] = s;
        }
        pl[4][t] = pooled4[t];
    }
    __syncthreads();
    if (t < 64) {
        float acc = 0.f;
        for (int l = 0; l < 5; ++l) {
            acc += pB[l * 64 + t];
            const float* wp = pW + l * 8192;
            const float* p = pl[l];
            for (int c = 0; c < 128; ++c) acc += p[c] * wp[c * 64 + t];
        }
        out[t] = acc;
    }
}

extern "C" void kernel_launch(void* const* d_in, const int* in_sizes, int n_in,
                              void* d_out, int out_size, void* d_ws, size_t ws_size,
                              hipStream_t stream) {
    const float* h0 = (const float*)d_in[0];
    const int* src = (const int*)d_in[1];
    const int* dst = (const int*)d_in[2];
    const float* W1 = (const float*)d_in[3];
    const float* W2 = (const float*)d_in[4];
    const float* bn1_g = (const float*)d_in[5];
    const float* bn1_b = (const float*)d_in[6];
    const float* bn2_g = (const float*)d_in[7];
    const float* bn2_b = (const float*)d_in[8];
    const float* pW = (const float*)d_in[9];
    const float* pB = (const float*)d_in[10];
    float* out = (float*)d_out;

    char* ws = (char*)d_ws;
    float* bufX = (float*)(ws + 0);             // 25.6 MB
    float* bufY = (float*)(ws + 25600000);      // 25.6 MB
    int* esrc = (int*)(ws + 51200000);          // 3.2 MB
    int* deg = (int*)(ws + 54400000);           // 200 KB
    int* row_start = (int*)(ws + 54600000);     // 200,004 B
    int* cursor = (int*)(ws + 54800016);        // 200 KB
    int* bsum = (int*)(ws + 55000016);          // 784 B
    int* boff = (int*)(ws + 55000800);          // 1 KB
    float* stats = (float*)(ws + 55001824);     // 8 KB: [bn1 x4][bn2 x4] x 256 f
    float* ppart = (float*)(ws + 55010016);     // 4 layers x 64 slots x 128 = 128 KB
    float* pooled4 = (float*)(ws + 55141088);   // 512 B
    bf16* WfH = (bf16*)(ws + 55141600);         // 256 KB
    bf16* WfL = (bf16*)(ws + 55403744);         // 256 KB

    init_kernel<<<196, 256, 0, stream>>>(deg, stats, ppart, pooled4);
    prep_kernel<<<64, 256, 0, stream>>>(W1, W2, WfH, WfL);
    hist_kernel<<<3125, 256, 0, stream>>>(dst, deg);
    scanA_kernel<<<196, 256, 0, stream>>>(deg, bsum);
    scanB_kernel<<<1, 256, 0, stream>>>(bsum, boff);
    scanC_kernel<<<196, 256, 0, stream>>>(deg, boff, row_start, cursor);
    fill_kernel<<<3125, 256, 0, stream>>>(src, dst, cursor, esrc);

    // Buffers: L_i: z -> zb, y1 -> yb, y2 -> zb (z dead after mm1; hprev dead after agg)
    for (int i = 0; i < 4; ++i) {
        float* zb = (i & 1) ? bufY : bufX;
        float* yb = (i & 1) ? bufX : bufY;
        const float* hprev = (i == 0) ? h0 : ((i & 1) ? bufX : bufY);
        if (i == 0) {
            agg_kernel<false><<<12500, 256, 0, stream>>>(hprev, esrc, row_start, nullptr,
                                                         nullptr, nullptr, zb, ppart);
        } else {
            agg_kernel<true><<<12500, 256, 0, stream>>>(
                hprev, esrc, row_start, stats + (4 + i - 1) * 256, bn2_g + (i - 1) * 128,
                bn2_b + (i - 1) * 128, zb, ppart + i * 8192);
        }
        mm_kernel<false><<<391, 256, 0, stream>>>(zb, WfH + i * 16384, WfL + i * 16384,
                                                  nullptr, nullptr, nullptr, yb,
                                                  stats + i * 256);
        mm_kernel<true><<<391, 256, 0, stream>>>(yb, WfH + (4 + i) * 16384,
                                                 WfL + (4 + i) * 16384, stats + i * 256,
                                                 bn1_g + i * 128, bn1_b + i * 128, zb,
                                                 stats + (4 + i) * 256);
    }
    // final y2 lives in bufY (layer 3: zb = bufY)
    pool_kernel<<<512, 256, 0, stream>>>(bufY, stats + 7 * 256, bn2_g + 3 * 128,
                                         bn2_b + 3 * 128, pooled4);
    head_kernel<<<1, 128, 0, stream>>>(ppart, pooled4, pW, pB, out);
}

// Round 5
// 661.942 us; speedup vs baseline: 1.6064x; 1.0460x over previous
//
#include <hip/hip_runtime.h>
#include <hip/hip_bf16.h>

#define N_NODES 50000
#define N_EDGES 800000
#define D 128

typedef __bf16 bf16;
typedef __attribute__((ext_vector_type(8))) __bf16 bf16x8;
typedef __attribute__((ext_vector_type(4))) __bf16 bf16x4;
typedef __attribute__((ext_vector_type(16))) float f32x16;
typedef _Float16 f16;
typedef __attribute__((ext_vector_type(2))) _Float16 f16x2;
typedef __attribute__((ext_vector_type(4))) _Float16 f16x4;

// ---------------- init: zero deg, stats, pooled ----------------
__global__ void init_kernel(int* __restrict__ deg, float* __restrict__ stats,
                            float* __restrict__ pooled) {
    int i = blockIdx.x * blockDim.x + threadIdx.x;
    if (i < N_NODES) deg[i] = 0;
    if (i < 2048) stats[i] = 0.f;
    if (i < 640) pooled[i] = 0.f;
}

// ---------------- W -> fragment-ordered bf16 hi/lo planes ----------------
// Frag layout (32x32x16 B-operand): col = lane&31, k = 8*(lane>>5)+j.
__global__ __launch_bounds__(256)
void prep_kernel(const float* __restrict__ W1, const float* __restrict__ W2,
                 bf16* __restrict__ WfH, bf16* __restrict__ WfL) {
    int gid = blockIdx.x * 256 + threadIdx.x;  // 0..16383
    int lane = gid & 63;
    int grp = gid >> 6;       // 0..255
    int sub = grp & 7;
    int cf = (grp >> 3) & 3;
    int m = grp >> 5;         // 0..7
    const float* Wsrc = (m < 4) ? (W1 + m * 16384) : (W2 + (m - 4) * 16384);
    int col = cf * 32 + (lane & 31);
    int kb = sub * 16 + 8 * (lane >> 5);
    bf16x8 h, l;
#pragma unroll
    for (int j = 0; j < 8; ++j) {
        float w = Wsrc[(kb + j) * 128 + col];
        bf16 hb = (bf16)w;
        bf16 lb = (bf16)(w - (float)hb);
        h[j] = hb;
        l[j] = lb;
    }
    int idx = m * 16384 + ((grp & 31) * 64 + lane) * 8;
    *(bf16x8*)&WfH[idx] = h;
    *(bf16x8*)&WfL[idx] = l;
}

// ---------------- degree histogram ----------------
__global__ void hist_kernel(const int* __restrict__ dst, int* __restrict__ deg) {
    int e = blockIdx.x * 256 + threadIdx.x;
    atomicAdd(&deg[dst[e]], 1);
}

// ---------------- parallel scan ----------------
__global__ __launch_bounds__(256)
void scanA_kernel(const int* __restrict__ deg, int* __restrict__ bsum) {
    __shared__ int red[256];
    int t = threadIdx.x;
    int g = blockIdx.x * 256 + t;
    red[t] = (g < N_NODES) ? deg[g] : 0;
    __syncthreads();
    for (int off = 128; off > 0; off >>= 1) {
        if (t < off) red[t] += red[t + off];
        __syncthreads();
    }
    if (t == 0) bsum[blockIdx.x] = red[0];
}

__global__ __launch_bounds__(256)
void scanB_kernel(const int* __restrict__ bsum, int* __restrict__ boff) {
    __shared__ int s[256];
    int t = threadIdx.x;
    s[t] = (t < 196) ? bsum[t] : 0;
    __syncthreads();
    for (int off = 1; off < 256; off <<= 1) {
        int a = (t >= off) ? s[t - off] : 0;
        __syncthreads();
        s[t] += a;
        __syncthreads();
    }
    boff[t] = (t == 0) ? 0 : s[t - 1];
}

__global__ __launch_bounds__(256)
void scanC_kernel(const int* __restrict__ deg, const int* __restrict__ boff,
                  int* __restrict__ row_start, int* __restrict__ cursor) {
    __shared__ int s[256];
    int t = threadIdx.x;
    int g = blockIdx.x * 256 + t;
    int v = (g < N_NODES) ? deg[g] : 0;
    s[t] = v;
    __syncthreads();
    for (int off = 1; off < 256; off <<= 1) {
        int a = (t >= off) ? s[t - off] : 0;
        __syncthreads();
        s[t] += a;
        __syncthreads();
    }
    int excl = boff[blockIdx.x] + s[t] - v;
    if (g < N_NODES) {
        row_start[g] = excl;
        cursor[g] = excl;
    }
    if (blockIdx.x == 0 && t == 0) row_start[N_NODES] = N_EDGES;
}

// ---------------- fill CSC edge list ----------------
__global__ void fill_kernel(const int* __restrict__ src, const int* __restrict__ dst,
                            int* __restrict__ cursor, int* __restrict__ esrc) {
    int e = blockIdx.x * 256 + threadIdx.x;
    int d = dst[e];
    int p = atomicAdd(&cursor[d], 1);
    esrc[p] = src[e];
}

// ---------------- conv: Hb = (fp16) f(Y); pooled += colsum f(Y) (fp32) ----------------
// f = relu(bn(.)) if APPLY else identity. STORE=false skips the Hb write (last layer).
template <bool APPLY, bool STORE>
__global__ __launch_bounds__(256)
void conv_kernel(const float* __restrict__ Y, const float* __restrict__ stats,
                 const float* __restrict__ gam, const float* __restrict__ bet,
                 f16* __restrict__ Hb, float* __restrict__ pooled) {
    __shared__ float abS[2][128];
    __shared__ float red[8][128];
    int t = threadIdx.x;
    if (APPLY && t < 128) {
        float s = stats[t] * (1.0f / N_NODES);
        float q = stats[128 + t] * (1.0f / N_NODES);
        float a = gam[t] * rsqrtf(q - s * s + 1e-5f);
        abS[0][t] = a;
        abS[1][t] = bet[t] - s * a;
    }
    __syncthreads();
    int c = (t & 31) << 2;
    int rrow = t >> 5;
    float4 A = make_float4(1.f, 1.f, 1.f, 1.f), B = make_float4(0.f, 0.f, 0.f, 0.f);
    if (APPLY) {
        A = *(const float4*)&abS[0][c];
        B = *(const float4*)&abS[1][c];
    }
    float4 p = make_float4(0.f, 0.f, 0.f, 0.f);
    for (int r = blockIdx.x * 8 + rrow; r < N_NODES; r += gridDim.x * 8) {
        float4 v = *(const float4*)&Y[r * D + c];
        if (APPLY) {
            v.x = fmaxf(fmaf(A.x, v.x, B.x), 0.f);
            v.y = fmaxf(fmaf(A.y, v.y, B.y), 0.f);
            v.z = fmaxf(fmaf(A.z, v.z, B.z), 0.f);
            v.w = fmaxf(fmaf(A.w, v.w, B.w), 0.f);
        }
        if (STORE) {
            f16x4 h4;
            h4[0] = (f16)v.x; h4[1] = (f16)v.y; h4[2] = (f16)v.z; h4[3] = (f16)v.w;
            *(f16x4*)&Hb[r * D + c] = h4;
        }
        p.x += v.x; p.y += v.y; p.z += v.z; p.w += v.w;
    }
    *(float4*)&red[rrow][c] = p;
    __syncthreads();
    if (t < 128) {
        float s = 0.f;
#pragma unroll
        for (int i = 0; i < 8; ++i) s += red[i][t];
        atomicAdd(&pooled[t], s);
    }
}

// ---------------- aggregation: z[v] = Hb[v] + sum_{e->v} Hb[src] (fp16 gather) --------
__global__ __launch_bounds__(256)
void agg_kernel(const f16* __restrict__ Hb, const int* __restrict__ esrc,
                const int* __restrict__ row_start, float* __restrict__ Z) {
    int v = blockIdx.x * 4 + (threadIdx.x >> 6);
    int lane = threadIdx.x & 63;
    int c2 = lane << 1;
    int beg = row_start[v], end_ = row_start[v + 1];
    f16x2 sv = *(const f16x2*)&Hb[v * D + c2];
    float ax = (float)sv[0], ay = (float)sv[1];
    int e = beg;
    for (; e + 4 <= end_; e += 4) {
        int s0 = esrc[e], s1 = esrc[e + 1], s2 = esrc[e + 2], s3 = esrc[e + 3];
        f16x2 v0 = *(const f16x2*)&Hb[s0 * D + c2];
        f16x2 v1 = *(const f16x2*)&Hb[s1 * D + c2];
        f16x2 v2 = *(const f16x2*)&Hb[s2 * D + c2];
        f16x2 v3 = *(const f16x2*)&Hb[s3 * D + c2];
        ax += (float)v0[0] + (float)v1[0] + (float)v2[0] + (float)v3[0];
        ay += (float)v0[1] + (float)v1[1] + (float)v2[1] + (float)v3[1];
    }
    for (; e < end_; ++e) {
        int s0 = esrc[e];
        f16x2 v0 = *(const f16x2*)&Hb[s0 * D + c2];
        ax += (float)v0[0];
        ay += (float)v0[1];
    }
    *(float2*)&Z[v * D + c2] = make_float2(ax, ay);
}

// ---------------- matmul: Y = f(X) @ W via split-bf16 MFMA ----------------
template <bool BN_IN>
__global__ __launch_bounds__(256, 2)
void mm_kernel(const float* __restrict__ X, const bf16* __restrict__ WfH,
               const bf16* __restrict__ WfL, const float* __restrict__ stats_in,
               const float* __restrict__ gam, const float* __restrict__ bet,
               float* __restrict__ Y, float* __restrict__ stats_out) {
    __shared__ bf16 Ah[4096];  // [128 rows][32 k], XOR-swizzled
    __shared__ bf16 Al[4096];
    __shared__ float ab[2][128];

    int t = threadIdx.x;
    int w = t >> 6, lane = t & 63;
    if (BN_IN && t < 128) {
        float s = stats_in[t] * (1.0f / N_NODES);
        float q = stats_in[128 + t] * (1.0f / N_NODES);
        float a = gam[t] * rsqrtf(q - s * s + 1e-5f);
        ab[0][t] = a;
        ab[1][t] = bet[t] - s * a;
    }

    bf16x8 Bh[8], Bl[8];
#pragma unroll
    for (int c = 0; c < 8; ++c) {
        int idx = ((w * 8 + c) * 64 + lane) * 8;
        Bh[c] = *(const bf16x8*)&WfH[idx];
        Bl[c] = *(const bf16x8*)&WfL[idx];
    }

    f32x16 acc[4];
#pragma unroll
    for (int fr = 0; fr < 4; ++fr) acc[fr] = (f32x16)0.0f;

    int rowbase = blockIdx.x * 128;
    int nrows = min(128, N_NODES - rowbase);
    int srow = t >> 1;
    int sk0 = (t & 1) * 16;
    __syncthreads();  // ab ready

    for (int kb = 0; kb < 4; ++kb) {
        if (kb) __syncthreads();
        {
            bool ok = srow < nrows;
            const float* xr = &X[(rowbase + srow) * 128 + kb * 32 + sk0];
#pragma unroll
            for (int i = 0; i < 4; ++i) {
                float4 v = make_float4(0.f, 0.f, 0.f, 0.f);
                if (ok) {
                    v = *(const float4*)&xr[i * 4];
                    if (BN_IN) {
                        int kg = kb * 32 + sk0 + i * 4;
                        v.x = fmaxf(fmaf(ab[0][kg + 0], v.x, ab[1][kg + 0]), 0.f);
                        v.y = fmaxf(fmaf(ab[0][kg + 1], v.y, ab[1][kg + 1]), 0.f);
                        v.z = fmaxf(fmaf(ab[0][kg + 2], v.z, ab[1][kg + 2]), 0.f);
                        v.w = fmaxf(fmaf(ab[0][kg + 3], v.w, ab[1][kg + 3]), 0.f);
                    }
                }
                bf16x4 h4, l4;
                h4[0] = (bf16)v.x; l4[0] = (bf16)(v.x - (float)h4[0]);
                h4[1] = (bf16)v.y; l4[1] = (bf16)(v.y - (float)h4[1]);
                h4[2] = (bf16)v.z; l4[2] = (bf16)(v.z - (float)h4[2]);
                h4[3] = (bf16)v.w; l4[3] = (bf16)(v.w - (float)h4[3]);
                int e = srow * 32 + sk0 + i * 4;
                int es = e ^ ((srow & 7) << 3);
                *(bf16x4*)&Ah[es] = h4;
                *(bf16x4*)&Al[es] = l4;
            }
        }
        __syncthreads();
#pragma unroll
        for (int s2 = 0; s2 < 2; ++s2) {
            int sg = kb * 2 + s2;
#pragma unroll
            for (int fr = 0; fr < 4; ++fr) {
                int row = fr * 32 + (lane & 31);
                int e = row * 32 + s2 * 16 + 8 * (lane >> 5);
                int es = e ^ ((row & 7) << 3);
                bf16x8 ah = *(const bf16x8*)&Ah[es];
                bf16x8 al = *(const bf16x8*)&Al[es];
                acc[fr] = __builtin_amdgcn_mfma_f32_32x32x16_bf16(al, Bl[sg], acc[fr], 0, 0, 0);
                acc[fr] = __builtin_amdgcn_mfma_f32_32x32x16_bf16(al, Bh[sg], acc[fr], 0, 0, 0);
                acc[fr] = __builtin_amdgcn_mfma_f32_32x32x16_bf16(ah, Bl[sg], acc[fr], 0, 0, 0);
                acc[fr] = __builtin_amdgcn_mfma_f32_32x32x16_bf16(ah, Bh[sg], acc[fr], 0, 0, 0);
            }
        }
    }

    // C/D frag: col = lane&31, row = (reg&3) + 8*(reg>>2) + 4*(lane>>5)
    int col = w * 32 + (lane & 31);
    float psum = 0.f, psq = 0.f;
#pragma unroll
    for (int fr = 0; fr < 4; ++fr) {
#pragma unroll
        for (int r = 0; r < 16; ++r) {
            float v = acc[fr][r];
            int row = fr * 32 + (r & 3) + 8 * (r >> 2) + 4 * (lane >> 5);
            if (row < nrows) Y[(rowbase + row) * 128 + col] = v;
            psum += v;
            psq += v * v;
        }
    }
    psum += __shfl_xor(psum, 32);
    psq += __shfl_xor(psq, 32);
    if (lane < 32) {
        atomicAdd(&stats_out[col], psum);
        atomicAdd(&stats_out[128 + col], psq);
    }
}

// ---------------- heads ----------------
__global__ void head_kernel(const float* __restrict__ pooled, const float* __restrict__ pW,
                            const float* __restrict__ pB, float* __restrict__ out) {
    int o = threadIdx.x;  // 64
    float acc = 0.f;
    for (int l = 0; l < 5; ++l) {
        acc += pB[l * 64 + o];
        const float* wp = pW + l * 8192;
        const float* p = pooled + l * 128;
        for (int c = 0; c < 128; ++c) acc += p[c] * wp[c * 64 + o];
    }
    out[o] = acc;
}

extern "C" void kernel_launch(void* const* d_in, const int* in_sizes, int n_in,
                              void* d_out, int out_size, void* d_ws, size_t ws_size,
                              hipStream_t stream) {
    const float* h0 = (const float*)d_in[0];
    const int* src = (const int*)d_in[1];
    const int* dst = (const int*)d_in[2];
    const float* W1 = (const float*)d_in[3];
    const float* W2 = (const float*)d_in[4];
    const float* bn1_g = (const float*)d_in[5];
    const float* bn1_b = (const float*)d_in[6];
    const float* bn2_g = (const float*)d_in[7];
    const float* bn2_b = (const float*)d_in[8];
    const float* pW = (const float*)d_in[9];
    const float* pB = (const float*)d_in[10];
    float* out = (float*)d_out;

    char* ws = (char*)d_ws;
    float* bufX = (float*)(ws + 0);             // z / y2, 25.6 MB
    float* bufY = (float*)(ws + 25600000);      // y1, 25.6 MB
    f16* hb = (f16*)(ws + 51200000);            // fp16 h, 12.8 MB
    int* esrc = (int*)(ws + 64000000);          // 3.2 MB
    int* deg = (int*)(ws + 67200000);           // 200 KB
    int* row_start = (int*)(ws + 67400000);     // 200,004 B (+pad)
    int* cursor = (int*)(ws + 67600016);        // 200 KB
    int* bsum = (int*)(ws + 67800016);          // 784 B (+pad)
    int* boff = (int*)(ws + 67801040);          // 1 KB
    float* stats = (float*)(ws + 67802064);     // 8 KB
    float* pooled = (float*)(ws + 67810256);    // 5*128 f
    bf16* WfH = (bf16*)(ws + 67812816);         // 256 KB
    bf16* WfL = (bf16*)(ws + 68074960);         // 256 KB

    init_kernel<<<196, 256, 0, stream>>>(deg, stats, pooled);
    prep_kernel<<<64, 256, 0, stream>>>(W1, W2, WfH, WfL);
    hist_kernel<<<3125, 256, 0, stream>>>(dst, deg);
    scanA_kernel<<<196, 256, 0, stream>>>(deg, bsum);
    scanB_kernel<<<1, 256, 0, stream>>>(bsum, boff);
    scanC_kernel<<<196, 256, 0, stream>>>(deg, boff, row_start, cursor);
    fill_kernel<<<3125, 256, 0, stream>>>(src, dst, cursor, esrc);
    // hidden_rep[0]: fp16-round h0 + pool
    conv_kernel<false, true><<<512, 256, 0, stream>>>(h0, nullptr, nullptr, nullptr, hb,
                                                      pooled);

    for (int i = 0; i < 4; ++i) {
        agg_kernel<<<12500, 256, 0, stream>>>(hb, esrc, row_start, bufX);
        mm_kernel<false><<<391, 256, 0, stream>>>(bufX, WfH + i * 16384, WfL + i * 16384,
                                                  nullptr, nullptr, nullptr, bufY,
                                                  stats + i * 256);
        mm_kernel<true><<<391, 256, 0, stream>>>(bufY, WfH + (4 + i) * 16384,
                                                 WfL + (4 + i) * 16384, stats + i * 256,
                                                 bn1_g + i * 128, bn1_b + i * 128, bufX,
                                                 stats + (4 + i) * 256);
        if (i < 3) {
            conv_kernel<true, true><<<512, 256, 0, stream>>>(
                bufX, stats + (4 + i) * 256, bn2_g + i * 128, bn2_b + i * 128, hb,
                pooled + (i + 1) * 128);
        } else {
            conv_kernel<true, false><<<512, 256, 0, stream>>>(
                bufX, stats + (4 + i) * 256, bn2_g + i * 128, bn2_b + i * 128, hb,
                pooled + (i + 1) * 128);
        }
    }
    head_kernel<<<1, 64, 0, stream>>>(pooled, pW, pB, out);
}